// Round 6
// baseline (164.337 us; speedup 1.0000x reference)
//
#include <hip/hip_runtime.h>

// Cubic B-spline interpolation (SplineInter), 2D, m=1024x1024, PAD=2.
// Grid: coeffs (1028 x 1028) float32, flat-clamped gather per reference.
//
// R1: row-vectorized gathers (4x dwordx4/point): 111 -> 48 us kernel.
// R2: 2 pts/thread MLP probe: no change -> gather-THROUGHPUT bound (~3.6
//     cyc per scattered 16B load request).
// R3: hist/scan/scatter/eval: 75 us. R4: fixed-CAP segments, 16B packed
//     scatter + LDS-patch eval: 53 us. Cross-round fit: scattered
//     PARTIAL-LINE stores cost ~7-10 cyc/request (L2 sector RMW).
// R5: block-local LDS count-sort before emission -> point-scatter becomes
//     runs of ~8 consecutive 16B slots (full 64B lines); tile id packed in
//     .w; points held in registers; nontemporal out stores in eval.

#define I1 1028
#define TOTAL (1028 * 1028)
#define NPTS_TILE 64            // grid cells per tile side
#define NTILE_SIDE 16           // 1024/64
#define NTILES 256
#define PATCH 68                // 64 + 4 halo/stencil reach
#define PATCH_STRIDE 69         // +1 pad (odd) vs 32 banks
#define BPT 4                   // eval blocks per tile
#define CAP 10240               // slots/tile (mean 8192, sd 90 -> +22 sd)
#define CHUNK 2048              // points per scatter block
#define ITERS (CHUNK / 256)     // 8

typedef float f4u __attribute__((ext_vector_type(4), aligned(4)));

__device__ __forceinline__ void basis4(float t, float w[4]) {
    float a = 1.0f - t;
    w[0] = a * a * a;                                // j=-1: (1-t)^3
    w[1] = (3.0f * t - 6.0f) * (t * t) + 4.0f;       // j=0
    float xi = t - 1.0f;
    w[2] = -(3.0f * xi + 6.0f) * (xi * xi) + 4.0f;   // j=1
    w[3] = t * t * t;                                // j=2
}

__device__ __forceinline__ void point_cell(float2 xy, int& P0, int& P1,
                                           float& t0, float& t1, bool& valid) {
    float xn0 = xy.x * 1024.0f - 0.5f;
    float xn1 = xy.y * 1024.0f - 0.5f;
    valid = (xn0 > -2.0f) && (xn0 < 1024.0f) &&
            (xn1 > -2.0f) && (xn1 < 1024.0f);
    float P0f = floorf(xn0);
    float P1f = floorf(xn1);
    P0 = (int)P0f;
    P1 = (int)P1f;
    t0 = xn0 - P0f;
    t1 = xn1 - P1f;
}

__device__ __forceinline__ int tile_of(int P0, int P1) {
    int ty = min(max(P0, 0), 1023) >> 6;
    int tx = min(max(P1, 0), 1023) >> 6;
    return ty * NTILE_SIDE + tx;
}

// Exact reference semantics: flat-clamped scalar gather (always correct).
__device__ __forceinline__ float eval_slow(const float* __restrict__ coeffs,
                                           int base, const float w0[4],
                                           const float w1[4]) {
    float acc = 0.0f;
#pragma unroll
    for (int j = 0; j < 4; ++j) {
        int r = base + (j - 1) * I1 - 1;
        float s = 0.0f;
#pragma unroll
        for (int k = 0; k < 4; ++k) {
            int idx = min(max(r + k, 0), TOTAL - 1);
            s = fmaf(coeffs[idx], w1[k], s);
        }
        acc = fmaf(s, w0[j], acc);
    }
    return acc;
}

// ---------------- scatter: block-local LDS count-sort, coalesced emission ---

__global__ __launch_bounds__(256) void scatter_kernel(
    const float2* __restrict__ x2, int* __restrict__ gcount,
    float4* __restrict__ spts, const float* __restrict__ coeffs,
    float* __restrict__ out, int n)
{
    __shared__ int h[NTILES];        // block-local tile counts
    __shared__ int lstart[NTILES];   // exclusive prefix of h
    __shared__ int gbase[NTILES];    // claimed global base per tile
    __shared__ int rankc[NTILES];    // pass-B cursors
    __shared__ int sA[NTILES], sB[NTILES];
    __shared__ float4 sbuf[CHUNK];   // 32 KB sorted staging

    int t = threadIdx.x;
    int lo = blockIdx.x * CHUNK;

    // ---- pass A: load points into registers, count tiles
    float2 pt[ITERS];
    int    ptile[ITERS];
    h[t] = 0;
    __syncthreads();
#pragma unroll
    for (int it = 0; it < ITERS; ++it) {
        int p = lo + it * 256 + t;
        float2 xy = (p < n) ? x2[p] : make_float2(0.5f, 0.5f);
        pt[it] = xy;
        int P0, P1; float t0, t1; bool valid;
        point_cell(xy, P0, P1, t0, t1, valid);
        int tile = tile_of(P0, P1);
        ptile[it] = tile;
        if (p < n) atomicAdd(&h[tile], 1);
        else ptile[it] = -1;
    }
    __syncthreads();

    // ---- exclusive scan over 256 bins (Hillis-Steele, ping-pong)
    int cnt = h[t];
    sA[t] = cnt;
    __syncthreads();
    int* src = sA; int* dst = sB;
#pragma unroll
    for (int d = 1; d < NTILES; d <<= 1) {
        dst[t] = src[t] + ((t >= d) ? src[t - d] : 0);
        __syncthreads();
        int* tmp = src; src = dst; dst = tmp;
    }
    lstart[t] = src[t] - cnt;        // exclusive prefix
    // ---- claim contiguous global slice for this block's tile runs
    gbase[t] = (cnt > 0) ? atomicAdd(&gcount[t], cnt) : 0;
    rankc[t] = 0;
    __syncthreads();

    // ---- pass B: scatter into LDS in tile-sorted order
#pragma unroll
    for (int it = 0; it < ITERS; ++it) {
        int tile = ptile[it];
        if (tile >= 0) {
            int r = atomicAdd(&rankc[tile], 1);
            float4 v;
            v.x = pt[it].x;
            v.y = pt[it].y;
            v.z = __int_as_float(lo + it * 256 + t);  // original index
            v.w = __int_as_float(tile);
            sbuf[lstart[tile] + r] = v;
        }
    }
    __syncthreads();

    // ---- emission: linear walk of sorted LDS -> coalesced run stores
    int total = lo + CHUNK <= n ? CHUNK : max(0, n - lo);
    for (int k = t; k < total; k += 256) {
        float4 e = sbuf[k];
        int tile = __float_as_int(e.w);
        int slot = gbase[tile] + (k - lstart[tile]);
        if (slot < CAP) {
            spts[(size_t)tile * CAP + slot] = e;   // full-line runs
        } else {
            // Overflow (statistically never): exact direct eval.
            float2 xy = make_float2(e.x, e.y);
            int p = __float_as_int(e.z);
            int P0, P1; float t0, t1; bool valid;
            point_cell(xy, P0, P1, t0, t1, valid);
            float w0[4], w1[4];
            basis4(t0, w0);
            basis4(t1, w1);
            int b = I1 * (2 + P0) + (2 + P1);
            out[p] = valid ? eval_slow(coeffs, b, w0, w1) : 0.0f;
        }
    }
}

// ---------------- eval from LDS patch ----------------

__global__ __launch_bounds__(256) void eval_kernel(
    const float4* __restrict__ spts, const int* __restrict__ gcount,
    const float* __restrict__ coeffs, float* __restrict__ out)
{
    __shared__ float s_tile[PATCH * PATCH_STRIDE];

    int tile = blockIdx.x >> 2;          // BPT = 4
    int chunk = blockIdx.x & (BPT - 1);
    int ty = tile >> 4;
    int tx = tile & (NTILE_SIDE - 1);
    int row0 = ty * NPTS_TILE;
    int col0 = tx * NPTS_TILE;

    // Stage 68x68 patch (always fully in-bounds: row0+67 <= 1027).
    for (int i = threadIdx.x; i < PATCH * PATCH; i += 256) {
        int r = i / PATCH;
        int c = i - r * PATCH;
        s_tile[r * PATCH_STRIDE + c] = coeffs[(row0 + r) * I1 + (col0 + c)];
    }
    __syncthreads();

    int count = min(gcount[tile], CAP);
    const float4* seg = spts + (size_t)tile * CAP;

    for (int q = chunk * 256 + (int)threadIdx.x; q < count; q += BPT * 256) {
        float4 v = seg[q];
        float2 xy = make_float2(v.x, v.y);
        int p = __float_as_int(v.z);

        int P0, P1; float t0, t1; bool valid;
        point_cell(xy, P0, P1, t0, t1, valid);

        float w0[4], w1[4];
        basis4(t0, w0);
        basis4(t1, w1);

        int lr = P0 + 1 - row0;   // stencil top row within patch
        int lc = P1 + 1 - col0;   // stencil left col within patch

        float acc;
        if (lr >= 0 && lr <= NPTS_TILE && lc >= 0 && lc <= NPTS_TILE) {
            acc = 0.0f;
#pragma unroll
            for (int j = 0; j < 4; ++j) {
                const float* row = &s_tile[(lr + j) * PATCH_STRIDE + lc];
                float s = fmaf(row[0], w1[0],
                          fmaf(row[1], w1[1],
                          fmaf(row[2], w1[2],
                               row[3] * w1[3])));
                acc = fmaf(s, w0[j], acc);
            }
        } else {
            int b = I1 * (2 + P0) + (2 + P1);
            acc = eval_slow(coeffs, b, w0, w1);
        }
        __builtin_nontemporal_store(valid ? acc : 0.0f, &out[p]);
    }
}

// ---------------- fallback (small ws): R2 direct kernel ----------------

__global__ __launch_bounds__(256) void spline_direct_kernel(
    const float* __restrict__ x, const float* __restrict__ coeffs,
    float* __restrict__ out, int n)
{
    int i = blockIdx.x * blockDim.x + threadIdx.x;
    if (i >= n) return;
    float2 xy = reinterpret_cast<const float2*>(x)[i];
    int P0, P1; float t0, t1; bool valid;
    point_cell(xy, P0, P1, t0, t1, valid);
    float w0[4], w1[4];
    basis4(t0, w0);
    basis4(t1, w1);
    int base = I1 * (2 + P0) + (2 + P1);
    bool interior = (base - I1 - 1 >= 0) && (base + 2 * I1 + 2 <= TOTAL - 1);
    float acc = 0.0f;
    if (interior) {
#pragma unroll
        for (int j = 0; j < 4; ++j) {
            f4u v = *reinterpret_cast<const f4u*>(coeffs + base + (j - 1) * I1 - 1);
            float s = fmaf(v.x, w1[0], fmaf(v.y, w1[1],
                      fmaf(v.z, w1[2], v.w * w1[3])));
            acc = fmaf(s, w0[j], acc);
        }
    } else {
        acc = eval_slow(coeffs, base, w0, w1);
    }
    out[i] = valid ? acc : 0.0f;
}

extern "C" void kernel_launch(void* const* d_in, const int* in_sizes, int n_in,
                              void* d_out, int out_size, void* d_ws, size_t ws_size,
                              hipStream_t stream) {
    const float* x = (const float*)d_in[0];       // [N,2]
    const float* coeffs = (const float*)d_in[1];  // [1028*1028]
    float* out = (float*)d_out;                   // [N]
    int n = in_sizes[0] / 2;                      // 2,097,152 points

    size_t need = 1024 + (size_t)NTILES * CAP * 16;
    if (ws_size < need) {
        int block = 256;
        int grid = (n + block - 1) / block;
        spline_direct_kernel<<<grid, block, 0, stream>>>(x, coeffs, out, n);
        return;
    }

    char* ws = (char*)d_ws;
    int* gcount  = (int*)ws;                 // 256 ints
    float4* spts = (float4*)(ws + 1024);     // NTILES * CAP float4

    const float2* x2 = (const float2*)x;
    int sblocks = (n + CHUNK - 1) / CHUNK;   // 1024

    hipMemsetAsync(gcount, 0, NTILES * sizeof(int), stream);
    scatter_kernel<<<sblocks, 256, 0, stream>>>(x2, gcount, spts, coeffs, out, n);
    eval_kernel<<<NTILES * BPT, 256, 0, stream>>>(spts, gcount, coeffs, out);
}

// Round 7
// 110.941 us; speedup vs baseline: 1.4813x; 1.4813x over previous
//
#include <hip/hip_runtime.h>

// Cubic B-spline interpolation (SplineInter), 2D, m=1024x1024, PAD=2.
// Grid: coeffs (1028 x 1028) float32, flat-clamped gather per reference.
//
// R1: row-vectorized gathers (4x dwordx4/point): 48 us kernel.
// R2: MLP probe: no change -> scattered-gather THROUGHPUT bound, ~3.6 cyc
//     per 16B line-lookup at TCP.
// R3-R5: sort-based pipelines all >= R2 (permutation always costs one full
//     scattered stream + extra passes; nontemporal scattered stores are
//     catastrophic: 94 MB HBM writes for 8 MB of data).
// R6: fat-grid precompute. Prep expands coeffs into fat[1024][1024] cells of
//     16 fp16 = 32B (one cache line covers the whole 4x4 stencil). Main
//     kernel: ONE 32B gather per point instead of four 16B line-lookups.

#define I1 1028
#define TOTAL (1028 * 1028)

typedef float f4u __attribute__((ext_vector_type(4), aligned(4)));
typedef _Float16 h16v __attribute__((ext_vector_type(16)));  // 32 B

#define PREP_ROWS 16     // cells per tile in y
#define PREP_COLS 64     // cells per tile in x
#define PREP_SROWS (PREP_ROWS + 3)   // 19 coeff rows staged
#define PREP_SCOLS (PREP_COLS + 3)   // 67 coeff cols staged

__device__ __forceinline__ void basis4(float t, float w[4]) {
    float a = 1.0f - t;
    w[0] = a * a * a;                                // j=-1: (1-t)^3
    w[1] = (3.0f * t - 6.0f) * (t * t) + 4.0f;       // j=0
    float xi = t - 1.0f;
    w[2] = -(3.0f * xi + 6.0f) * (xi * xi) + 4.0f;   // j=1
    w[3] = t * t * t;                                // j=2
}

__device__ __forceinline__ void point_cell(float2 xy, int& P0, int& P1,
                                           float& t0, float& t1, bool& valid) {
    float xn0 = xy.x * 1024.0f - 0.5f;
    float xn1 = xy.y * 1024.0f - 0.5f;
    valid = (xn0 > -2.0f) && (xn0 < 1024.0f) &&
            (xn1 > -2.0f) && (xn1 < 1024.0f);
    float P0f = floorf(xn0);
    float P1f = floorf(xn1);
    P0 = (int)P0f;
    P1 = (int)P1f;
    t0 = xn0 - P0f;
    t1 = xn1 - P1f;
}

// Exact reference semantics: flat-clamped scalar gather (always correct).
__device__ __forceinline__ float eval_slow(const float* __restrict__ coeffs,
                                           int base, const float w0[4],
                                           const float w1[4]) {
    float acc = 0.0f;
#pragma unroll
    for (int j = 0; j < 4; ++j) {
        int r = base + (j - 1) * I1 - 1;
        float s = 0.0f;
#pragma unroll
        for (int k = 0; k < 4; ++k) {
            int idx = min(max(r + k, 0), TOTAL - 1);
            s = fmaf(coeffs[idx], w1[k], s);
        }
        acc = fmaf(s, w0[j], acc);
    }
    return acc;
}

// ---------------- prep: expand coeffs -> fat fp16 stencil grid -------------
// Cell (r,c), r,c in [0,1024): fat[r*1024+c][j*4+k] = coeffs[(r+1+j)*1028
// + (c+1+k)]  (all indices in-bounds for the full cell range; no clamping).

__global__ __launch_bounds__(256) void prep_kernel(
    const float* __restrict__ coeffs, h16v* __restrict__ fat)
{
    __shared__ float s[PREP_SROWS * PREP_SCOLS];  // 19*67 floats, odd stride

    int tile_x = blockIdx.x & 15;       // 1024/64 = 16 tiles in x
    int tile_y = blockIdx.x >> 4;       // 1024/16 = 64 tiles in y
    int r0 = tile_y * PREP_ROWS;
    int c0 = tile_x * PREP_COLS;
    int t = threadIdx.x;

    for (int i = t; i < PREP_SROWS * PREP_SCOLS; i += 256) {
        int rr = i / PREP_SCOLS;
        int cc = i - rr * PREP_SCOLS;
        s[i] = coeffs[(r0 + 1 + rr) * I1 + (c0 + 1 + cc)];
    }
    __syncthreads();

#pragma unroll
    for (int ii = 0; ii < (PREP_ROWS * PREP_COLS) / 256; ++ii) {
        int l = ii * 256 + t;
        int lr = l >> 6;          // /64
        int lc = l & 63;
        h16v v;
#pragma unroll
        for (int j = 0; j < 4; ++j) {
#pragma unroll
            for (int k = 0; k < 4; ++k) {
                v[j * 4 + k] = (_Float16)s[(lr + j) * PREP_SCOLS + (lc + k)];
            }
        }
        fat[(size_t)(r0 + lr) * 1024 + (c0 + lc)] = v;  // 32B coalesced store
    }
}

// ---------------- main: one 32B gather per point ---------------------------

__global__ __launch_bounds__(256) void fat_eval_kernel(
    const float* __restrict__ x, const h16v* __restrict__ fat,
    const float* __restrict__ coeffs, float* __restrict__ out, int n)
{
    int i = blockIdx.x * blockDim.x + threadIdx.x;
    if (i >= n) return;

    float2 xy = reinterpret_cast<const float2*>(x)[i];
    int P0, P1; float t0, t1; bool valid;
    point_cell(xy, P0, P1, t0, t1, valid);

    float w0[4], w1[4];
    basis4(t0, w0);
    basis4(t1, w1);

    float acc = 0.0f;
    if (valid) {
        if (P0 >= 0 && P1 >= 0) {   // P0,P1 <= 1023 guaranteed by valid
            h16v v = fat[(size_t)P0 * 1024 + P1];  // one 64B-line gather
#pragma unroll
            for (int j = 0; j < 4; ++j) {
                float s = fmaf((float)v[j * 4 + 0], w1[0],
                          fmaf((float)v[j * 4 + 1], w1[1],
                          fmaf((float)v[j * 4 + 2], w1[2],
                               (float)v[j * 4 + 3] * w1[3])));
                acc = fmaf(s, w0[j], acc);
            }
        } else {
            // Rare boundary cells (P<0): exact flat-clamped fp32 path.
            int base = I1 * (2 + P0) + (2 + P1);
            acc = eval_slow(coeffs, base, w0, w1);
        }
    }
    out[i] = valid ? acc : 0.0f;
}

// ---------------- fallback (small ws): R2 direct kernel --------------------

__global__ __launch_bounds__(256) void spline_direct_kernel(
    const float* __restrict__ x, const float* __restrict__ coeffs,
    float* __restrict__ out, int n)
{
    int i = blockIdx.x * blockDim.x + threadIdx.x;
    if (i >= n) return;
    float2 xy = reinterpret_cast<const float2*>(x)[i];
    int P0, P1; float t0, t1; bool valid;
    point_cell(xy, P0, P1, t0, t1, valid);
    float w0[4], w1[4];
    basis4(t0, w0);
    basis4(t1, w1);
    int base = I1 * (2 + P0) + (2 + P1);
    bool interior = (base - I1 - 1 >= 0) && (base + 2 * I1 + 2 <= TOTAL - 1);
    float acc = 0.0f;
    if (interior) {
#pragma unroll
        for (int j = 0; j < 4; ++j) {
            f4u v = *reinterpret_cast<const f4u*>(coeffs + base + (j - 1) * I1 - 1);
            float s = fmaf(v.x, w1[0], fmaf(v.y, w1[1],
                      fmaf(v.z, w1[2], v.w * w1[3])));
            acc = fmaf(s, w0[j], acc);
        }
    } else {
        acc = eval_slow(coeffs, base, w0, w1);
    }
    out[i] = valid ? acc : 0.0f;
}

extern "C" void kernel_launch(void* const* d_in, const int* in_sizes, int n_in,
                              void* d_out, int out_size, void* d_ws, size_t ws_size,
                              hipStream_t stream) {
    const float* x = (const float*)d_in[0];       // [N,2]
    const float* coeffs = (const float*)d_in[1];  // [1028*1028]
    float* out = (float*)d_out;                   // [N]
    int n = in_sizes[0] / 2;                      // 2,097,152 points

    size_t need = (size_t)1024 * 1024 * 32;       // 32 MB fat grid
    if (ws_size < need) {
        int block = 256;
        int grid = (n + block - 1) / block;
        spline_direct_kernel<<<grid, block, 0, stream>>>(x, coeffs, out, n);
        return;
    }

    h16v* fat = (h16v*)d_ws;

    // 1024 blocks: each builds a 16x64-cell slab of the fat grid.
    prep_kernel<<<(1024 / PREP_ROWS) * (1024 / PREP_COLS), 256, 0, stream>>>(
        coeffs, fat);

    int block = 256;
    int grid = (n + block - 1) / block;
    fat_eval_kernel<<<grid, block, 0, stream>>>(x, fat, coeffs, out, n);
}